// Round 1
// baseline (979.542 us; speedup 1.0000x reference)
//
#include <hip/hip_runtime.h>
#include <math.h>

#define NPTS 120000
#define NLID 100000
#define NRAD 20000
#define NCH 64
#define MAPW 512
#define MAPHW (512 * 512)
#define BLOCK 128

__device__ __forceinline__ float gelu_f(float x) {
    // exact GELU: x * 0.5 * (1 + erf(x / sqrt(2)))
    return 0.5f * x * (1.0f + erff(x * 0.7071067811865476f));
}

__global__ __launch_bounds__(BLOCK) void fbseg_kernel(
    const float* __restrict__ p0, const float* __restrict__ p1,
    const float* __restrict__ fl,
    const int* __restrict__ lidar, const int* __restrict__ radar,
    const float* __restrict__ w_lin, const float* __restrict__ b_lin,
    const float* __restrict__ w1, const float* __restrict__ b1,
    const float* __restrict__ w2, const float* __restrict__ b2,
    const float* __restrict__ w3, const float* __restrict__ b3,
    const float* __restrict__ w4, const float* __restrict__ b4,
    float* __restrict__ out)
{
    // per-thread scratch column: xs[k*BLOCK + tid]; lanes hit distinct banks
    // (2 lanes/bank = conflict-free). No __syncthreads needed (private columns).
    __shared__ float xs[NCH * BLOCK];
    const int tid = threadIdx.x;
    const int p = blockIdx.x * BLOCK + tid;
    if (p >= 2 * NPTS) return;  // 240000 % 128 == 0, guard is vestigial

    const int b = p / NPTS;
    const int i = p - b * NPTS;
    int r, c;
    if (i < NLID) {
        const int* cd = lidar + (size_t)(b * NLID + i) * 3;
        r = cd[1]; c = cd[2];
    } else {
        const int* cd = radar + (size_t)(b * NRAD + (i - NLID)) * 3;
        r = cd[1]; c = cd[2];
    }
    const size_t base = (size_t)b * ((size_t)NCH * MAPHW) + (size_t)r * MAPW + (size_t)c;

    float acc[NCH];
    #pragma unroll
    for (int j = 0; j < 64; j++) acc[j] = b_lin[j];

    // ---- layer lin, f0 half: pc += f0 @ w_lin[0:64] ----
    #pragma unroll 1
    for (int kk = 0; kk < 8; kk++) {
        float xv[8];
        #pragma unroll
        for (int u = 0; u < 8; u++)
            xv[u] = p0[base + (size_t)(kk * 8 + u) * MAPHW];
        #pragma unroll
        for (int u = 0; u < 8; u++) {
            const float* wr = w_lin + (kk * 8 + u) * 64;
            #pragma unroll
            for (int j = 0; j < 64; j++) acc[j] = fmaf(xv[u], wr[j], acc[j]);
        }
    }
    // ---- layer lin, f1 half: pc += f1 @ w_lin[64:128] ----
    #pragma unroll 1
    for (int kk = 0; kk < 8; kk++) {
        float xv[8];
        #pragma unroll
        for (int u = 0; u < 8; u++)
            xv[u] = p1[base + (size_t)(kk * 8 + u) * MAPHW];
        #pragma unroll
        for (int u = 0; u < 8; u++) {
            const float* wr = w_lin + (64 + kk * 8 + u) * 64;
            #pragma unroll
            for (int j = 0; j < 64; j++) acc[j] = fmaf(xv[u], wr[j], acc[j]);
        }
    }

    // ---- layer 1: h1 = gelu([pc, ff] @ w1 + b1) ----
    #pragma unroll
    for (int j = 0; j < 64; j++) xs[j * BLOCK + tid] = acc[j];  // stash pc
    #pragma unroll
    for (int j = 0; j < 64; j++) acc[j] = b1[j];
    #pragma unroll 2
    for (int k = 0; k < 64; k++) {
        float x = xs[k * BLOCK + tid];
        const float* wr = w1 + k * 64;
        #pragma unroll
        for (int j = 0; j < 64; j++) acc[j] = fmaf(x, wr[j], acc[j]);
    }
    #pragma unroll 1
    for (int kk = 0; kk < 8; kk++) {
        float xv[8];
        #pragma unroll
        for (int u = 0; u < 8; u++)
            xv[u] = fl[base + (size_t)(kk * 8 + u) * MAPHW];
        #pragma unroll
        for (int u = 0; u < 8; u++) {
            const float* wr = w1 + (64 + kk * 8 + u) * 64;
            #pragma unroll
            for (int j = 0; j < 64; j++) acc[j] = fmaf(xv[u], wr[j], acc[j]);
        }
    }
    #pragma unroll
    for (int j = 0; j < 64; j++) acc[j] = gelu_f(acc[j]);

    // ---- layer 2: h2 = gelu(h1 @ w2 + b2), 64 -> 32 ----
    #pragma unroll
    for (int j = 0; j < 64; j++) xs[j * BLOCK + tid] = acc[j];
    #pragma unroll
    for (int j = 0; j < 32; j++) acc[j] = b2[j];
    #pragma unroll 2
    for (int k = 0; k < 64; k++) {
        float x = xs[k * BLOCK + tid];
        const float* wr = w2 + k * 32;
        #pragma unroll
        for (int j = 0; j < 32; j++) acc[j] = fmaf(x, wr[j], acc[j]);
    }
    #pragma unroll
    for (int j = 0; j < 32; j++) acc[j] = gelu_f(acc[j]);

    // ---- layer 3: h3 = gelu(h2 @ w3 + b3), 32 -> 16 ----
    #pragma unroll
    for (int j = 0; j < 32; j++) xs[j * BLOCK + tid] = acc[j];
    #pragma unroll
    for (int j = 0; j < 16; j++) acc[j] = b3[j];
    #pragma unroll 2
    for (int k = 0; k < 32; k++) {
        float x = xs[k * BLOCK + tid];
        const float* wr = w3 + k * 16;
        #pragma unroll
        for (int j = 0; j < 16; j++) acc[j] = fmaf(x, wr[j], acc[j]);
    }
    #pragma unroll
    for (int j = 0; j < 16; j++) acc[j] = gelu_f(acc[j]);

    // ---- layer 4: s = sigmoid(h3 @ w4 + b4), 16 -> 1 ----
    float s = b4[0];
    #pragma unroll
    for (int k = 0; k < 16; k++) s = fmaf(acc[k], w4[k], s);
    out[p] = 1.0f / (1.0f + expf(-s));
}

extern "C" void kernel_launch(void* const* d_in, const int* in_sizes, int n_in,
                              void* d_out, int out_size, void* d_ws, size_t ws_size,
                              hipStream_t stream) {
    const float* p0    = (const float*)d_in[0];
    const float* p1    = (const float*)d_in[1];
    const float* fl    = (const float*)d_in[2];
    const int*   lidar = (const int*)d_in[3];
    const int*   radar = (const int*)d_in[4];
    const float* w_lin = (const float*)d_in[5];
    const float* b_lin = (const float*)d_in[6];
    const float* w1    = (const float*)d_in[7];
    const float* b1    = (const float*)d_in[8];
    const float* w2    = (const float*)d_in[9];
    const float* b2    = (const float*)d_in[10];
    const float* w3    = (const float*)d_in[11];
    const float* b3    = (const float*)d_in[12];
    const float* w4    = (const float*)d_in[13];
    const float* b4    = (const float*)d_in[14];
    float* out = (float*)d_out;

    const int total = 2 * NPTS;
    dim3 grid((total + BLOCK - 1) / BLOCK), block(BLOCK);
    hipLaunchKernelGGL(fbseg_kernel, grid, block, 0, stream,
                       p0, p1, fl, lidar, radar,
                       w_lin, b_lin, w1, b1, w2, b2, w3, b3, w4, b4, out);
}

// Round 2
// 570.711 us; speedup vs baseline: 1.7164x; 1.7164x over previous
//
#include <hip/hip_runtime.h>
#include <math.h>

#define NPTS 120000
#define NLID 100000
#define NRAD 20000
#define NTOT (2 * NPTS)
#define NCH 64
#define MAPW 512
#define MAPHW (512 * 512)
#define BLOCK 128
#define NBINS 16384  // (b:1)(r:9)(c>>5:4) = 14 bits

__device__ __forceinline__ float gelu_f(float x) {
    return 0.5f * x * (1.0f + erff(x * 0.7071067811865476f));
}

// decode global point id -> (b, r, c)
__device__ __forceinline__ void point_rc(int p, const int* __restrict__ lidar,
                                         const int* __restrict__ radar,
                                         int& b, int& r, int& c) {
    b = p / NPTS;
    int i = p - b * NPTS;
    if (i < NLID) {
        const int* cd = lidar + (size_t)(b * NLID + i) * 3;
        r = cd[1]; c = cd[2];
    } else {
        const int* cd = radar + (size_t)(b * NRAD + (i - NLID)) * 3;
        r = cd[1]; c = cd[2];
    }
}

__device__ __forceinline__ int bin_key(int b, int r, int c) {
    return (b << 13) | (r << 4) | (c >> 5);
}

__global__ void hist_kernel(const int* __restrict__ lidar, const int* __restrict__ radar,
                            int* __restrict__ hist) {
    int p = blockIdx.x * blockDim.x + threadIdx.x;
    if (p >= NTOT) return;
    int b, r, c;
    point_rc(p, lidar, radar, b, r, c);
    atomicAdd(&hist[bin_key(b, r, c)], 1);
}

__global__ __launch_bounds__(1024) void scan_kernel(const int* __restrict__ hist,
                                                    int* __restrict__ offs) {
    __shared__ int sums[1024];
    const int t = threadIdx.x;
    int local[16];
    int s = 0;
    #pragma unroll
    for (int i = 0; i < 16; i++) { local[i] = hist[t * 16 + i]; s += local[i]; }
    sums[t] = s;
    __syncthreads();
    for (int off = 1; off < 1024; off <<= 1) {
        int add = (t >= off) ? sums[t - off] : 0;
        __syncthreads();
        sums[t] += add;
        __syncthreads();
    }
    int excl = (t == 0) ? 0 : sums[t - 1];
    #pragma unroll
    for (int i = 0; i < 16; i++) { offs[t * 16 + i] = excl; excl += local[i]; }
}

__global__ void scatter_kernel(const int* __restrict__ lidar, const int* __restrict__ radar,
                               int* __restrict__ offs, int2* __restrict__ sorted) {
    int p = blockIdx.x * blockDim.x + threadIdx.x;
    if (p >= NTOT) return;
    int b, r, c;
    point_rc(p, lidar, radar, b, r, c);
    int pos = atomicAdd(&offs[bin_key(b, r, c)], 1);
    sorted[pos] = make_int2(p, (r << 9) | c);
}

__global__ __launch_bounds__(BLOCK) void fbseg_kernel(
    const float* __restrict__ p0, const float* __restrict__ p1,
    const float* __restrict__ fl,
    const int2* __restrict__ sorted,
    const float* __restrict__ w_lin, const float* __restrict__ b_lin,
    const float* __restrict__ w1, const float* __restrict__ b1,
    const float* __restrict__ w2, const float* __restrict__ b2,
    const float* __restrict__ w3, const float* __restrict__ b3,
    const float* __restrict__ w4, const float* __restrict__ b4,
    float* __restrict__ out)
{
    __shared__ float xs[NCH * BLOCK];
    const int tid = threadIdx.x;
    const int p = blockIdx.x * BLOCK + tid;
    if (p >= NTOT) return;

    const int2 e = sorted[p];
    const int orig = e.x;
    const int b = orig / NPTS;
    const int r = (e.y >> 9) & 511;
    const int c = e.y & 511;
    const size_t base = (size_t)b * ((size_t)NCH * MAPHW) + (size_t)r * MAPW + (size_t)c;

    float acc[NCH];
    #pragma unroll
    for (int j = 0; j < 64; j++) acc[j] = b_lin[j];

    // ---- layer lin, f0 half ----
    #pragma unroll 1
    for (int kk = 0; kk < 8; kk++) {
        float xv[8];
        #pragma unroll
        for (int u = 0; u < 8; u++)
            xv[u] = p0[base + (size_t)(kk * 8 + u) * MAPHW];
        #pragma unroll
        for (int u = 0; u < 8; u++) {
            const float* wr = w_lin + (kk * 8 + u) * 64;
            #pragma unroll
            for (int j = 0; j < 64; j++) acc[j] = fmaf(xv[u], wr[j], acc[j]);
        }
    }
    // ---- layer lin, f1 half ----
    #pragma unroll 1
    for (int kk = 0; kk < 8; kk++) {
        float xv[8];
        #pragma unroll
        for (int u = 0; u < 8; u++)
            xv[u] = p1[base + (size_t)(kk * 8 + u) * MAPHW];
        #pragma unroll
        for (int u = 0; u < 8; u++) {
            const float* wr = w_lin + (64 + kk * 8 + u) * 64;
            #pragma unroll
            for (int j = 0; j < 64; j++) acc[j] = fmaf(xv[u], wr[j], acc[j]);
        }
    }

    // ---- layer 1: h1 = gelu([pc, ff] @ w1 + b1) ----
    #pragma unroll
    for (int j = 0; j < 64; j++) xs[j * BLOCK + tid] = acc[j];
    #pragma unroll
    for (int j = 0; j < 64; j++) acc[j] = b1[j];
    #pragma unroll 2
    for (int k = 0; k < 64; k++) {
        float x = xs[k * BLOCK + tid];
        const float* wr = w1 + k * 64;
        #pragma unroll
        for (int j = 0; j < 64; j++) acc[j] = fmaf(x, wr[j], acc[j]);
    }
    #pragma unroll 1
    for (int kk = 0; kk < 8; kk++) {
        float xv[8];
        #pragma unroll
        for (int u = 0; u < 8; u++)
            xv[u] = fl[base + (size_t)(kk * 8 + u) * MAPHW];
        #pragma unroll
        for (int u = 0; u < 8; u++) {
            const float* wr = w1 + (64 + kk * 8 + u) * 64;
            #pragma unroll
            for (int j = 0; j < 64; j++) acc[j] = fmaf(xv[u], wr[j], acc[j]);
        }
    }
    #pragma unroll
    for (int j = 0; j < 64; j++) acc[j] = gelu_f(acc[j]);

    // ---- layer 2: 64 -> 32 ----
    #pragma unroll
    for (int j = 0; j < 64; j++) xs[j * BLOCK + tid] = acc[j];
    #pragma unroll
    for (int j = 0; j < 32; j++) acc[j] = b2[j];
    #pragma unroll 2
    for (int k = 0; k < 64; k++) {
        float x = xs[k * BLOCK + tid];
        const float* wr = w2 + k * 32;
        #pragma unroll
        for (int j = 0; j < 32; j++) acc[j] = fmaf(x, wr[j], acc[j]);
    }
    #pragma unroll
    for (int j = 0; j < 32; j++) acc[j] = gelu_f(acc[j]);

    // ---- layer 3: 32 -> 16 ----
    #pragma unroll
    for (int j = 0; j < 32; j++) xs[j * BLOCK + tid] = acc[j];
    #pragma unroll
    for (int j = 0; j < 16; j++) acc[j] = b3[j];
    #pragma unroll 2
    for (int k = 0; k < 32; k++) {
        float x = xs[k * BLOCK + tid];
        const float* wr = w3 + k * 16;
        #pragma unroll
        for (int j = 0; j < 16; j++) acc[j] = fmaf(x, wr[j], acc[j]);
    }
    #pragma unroll
    for (int j = 0; j < 16; j++) acc[j] = gelu_f(acc[j]);

    // ---- layer 4 + sigmoid ----
    float s = b4[0];
    #pragma unroll
    for (int k = 0; k < 16; k++) s = fmaf(acc[k], w4[k], s);
    out[orig] = 1.0f / (1.0f + expf(-s));
}

extern "C" void kernel_launch(void* const* d_in, const int* in_sizes, int n_in,
                              void* d_out, int out_size, void* d_ws, size_t ws_size,
                              hipStream_t stream) {
    const float* p0    = (const float*)d_in[0];
    const float* p1    = (const float*)d_in[1];
    const float* fl    = (const float*)d_in[2];
    const int*   lidar = (const int*)d_in[3];
    const int*   radar = (const int*)d_in[4];
    const float* w_lin = (const float*)d_in[5];
    const float* b_lin = (const float*)d_in[6];
    const float* w1    = (const float*)d_in[7];
    const float* b1    = (const float*)d_in[8];
    const float* w2    = (const float*)d_in[9];
    const float* b2    = (const float*)d_in[10];
    const float* w3    = (const float*)d_in[11];
    const float* b3    = (const float*)d_in[12];
    const float* w4    = (const float*)d_in[13];
    const float* b4    = (const float*)d_in[14];
    float* out = (float*)d_out;

    // ws layout: hist[NBINS] | offs[NBINS] | sorted[NTOT] (int2)
    char* ws = (char*)d_ws;
    int*  hist   = (int*)ws;
    int*  offs   = (int*)(ws + NBINS * sizeof(int));
    int2* sorted = (int2*)(ws + 2 * NBINS * sizeof(int));
    const size_t needed = 2 * NBINS * sizeof(int) + (size_t)NTOT * sizeof(int2);
    (void)needed; (void)ws_size;

    hipMemsetAsync(hist, 0, NBINS * sizeof(int), stream);
    hipLaunchKernelGGL(hist_kernel, dim3((NTOT + 255) / 256), dim3(256), 0, stream,
                       lidar, radar, hist);
    hipLaunchKernelGGL(scan_kernel, dim3(1), dim3(1024), 0, stream, hist, offs);
    hipLaunchKernelGGL(scatter_kernel, dim3((NTOT + 255) / 256), dim3(256), 0, stream,
                       lidar, radar, offs, sorted);
    hipLaunchKernelGGL(fbseg_kernel, dim3(NTOT / BLOCK), dim3(BLOCK), 0, stream,
                       p0, p1, fl, sorted,
                       w_lin, b_lin, w1, b1, w2, b2, w3, b3, w4, b4, out);
}

// Round 3
// 423.550 us; speedup vs baseline: 2.3127x; 1.3474x over previous
//
#include <hip/hip_runtime.h>
#include <math.h>

#define NPTS 120000
#define NLID 100000
#define NRAD 20000
#define NTOT (2 * NPTS)
#define MAPW 512
#define MAPHW (512 * 512)
#define NBINS 16384  // (b:1)(r:9)(c>>5:4)

typedef short sh8 __attribute__((ext_vector_type(8)));
typedef float f32x4 __attribute__((ext_vector_type(4)));
typedef unsigned short u16;

#define FSTR 200  // feat row stride (192+8) in shorts
#define H1S 72    // 64+8
#define H2S 40    // 32+8
#define H3S 24    // 16+8

__device__ __forceinline__ float gelu_f(float x) {
    return 0.5f * x * (1.0f + erff(x * 0.7071067811865476f));
}
__device__ __forceinline__ u16 f2bf(float f) {  // RNE
    unsigned int u = __float_as_uint(f);
    return (u16)((u + 0x7FFFu + ((u >> 16) & 1u)) >> 16);
}
__device__ __forceinline__ float bf2f(u16 h) {
    return __uint_as_float((unsigned int)h << 16);
}

// ---------------- sort chain (unchanged from R2) ----------------
__device__ __forceinline__ void point_rc(int p, const int* __restrict__ lidar,
                                         const int* __restrict__ radar,
                                         int& b, int& r, int& c) {
    b = p / NPTS;
    int i = p - b * NPTS;
    if (i < NLID) {
        const int* cd = lidar + (size_t)(b * NLID + i) * 3;
        r = cd[1]; c = cd[2];
    } else {
        const int* cd = radar + (size_t)(b * NRAD + (i - NLID)) * 3;
        r = cd[1]; c = cd[2];
    }
}
__device__ __forceinline__ int bin_key(int b, int r, int c) {
    return (b << 13) | (r << 4) | (c >> 5);
}
__global__ void hist_kernel(const int* __restrict__ lidar, const int* __restrict__ radar,
                            int* __restrict__ hist) {
    int p = blockIdx.x * blockDim.x + threadIdx.x;
    if (p >= NTOT) return;
    int b, r, c; point_rc(p, lidar, radar, b, r, c);
    atomicAdd(&hist[bin_key(b, r, c)], 1);
}
__global__ __launch_bounds__(1024) void scan_kernel(const int* __restrict__ hist,
                                                    int* __restrict__ offs) {
    __shared__ int sums[1024];
    const int t = threadIdx.x;
    int local[16]; int s = 0;
    #pragma unroll
    for (int i = 0; i < 16; i++) { local[i] = hist[t * 16 + i]; s += local[i]; }
    sums[t] = s;
    __syncthreads();
    for (int off = 1; off < 1024; off <<= 1) {
        int add = (t >= off) ? sums[t - off] : 0;
        __syncthreads();
        sums[t] += add;
        __syncthreads();
    }
    int excl = (t == 0) ? 0 : sums[t - 1];
    #pragma unroll
    for (int i = 0; i < 16; i++) { offs[t * 16 + i] = excl; excl += local[i]; }
}
__global__ void scatter_kernel(const int* __restrict__ lidar, const int* __restrict__ radar,
                               int* __restrict__ offs, int2* __restrict__ sorted) {
    int p = blockIdx.x * blockDim.x + threadIdx.x;
    if (p >= NTOT) return;
    int b, r, c; point_rc(p, lidar, radar, b, r, c);
    int pos = atomicAdd(&offs[bin_key(b, r, c)], 1);
    sorted[pos] = make_int2(p, (r << 9) | c);
}

// ---------------- weight prep: fuse lin+l1, swizzle to B-frag order ----------------
// wfrag1: 12288 u16, wfrag2: 2048 u16, wfrag3: 512 u16, b_eff: 64 f32
__global__ void wprep_kernel(const float* __restrict__ w_lin, const float* __restrict__ b_lin,
                             const float* __restrict__ w1, const float* __restrict__ b1,
                             const float* __restrict__ w2, const float* __restrict__ w3,
                             u16* __restrict__ wfrag1, u16* __restrict__ wfrag2,
                             u16* __restrict__ wfrag3, float* __restrict__ b_eff) {
    int e = blockIdx.x * blockDim.x + threadIdx.x;
    if (e < 12288) {
        int fi = e >> 9, r = e & 511, lane = r >> 3, j = r & 7;
        int kk = fi >> 2, nt = fi & 3;
        int k = kk * 32 + (lane >> 4) * 8 + j;
        int n = nt * 16 + (lane & 15);
        float val;
        if (k < 128) {
            float s = 0.f;
            for (int jj = 0; jj < 64; jj++) s += w_lin[k * 64 + jj] * w1[jj * 64 + n];
            val = s;
        } else {
            val = w1[(k - 64) * 64 + n];
        }
        wfrag1[e] = f2bf(val);
    } else if (e < 12288 + 2048) {
        int e2 = e - 12288;
        int fi = e2 >> 9, lane = (e2 >> 3) & 63, j = e2 & 7;
        int kk = fi >> 1, nt = fi & 1;
        int k = kk * 32 + (lane >> 4) * 8 + j;
        int n = nt * 16 + (lane & 15);
        wfrag2[e2] = f2bf(w2[k * 32 + n]);
    } else if (e < 12288 + 2048 + 512) {
        int e3 = e - 12288 - 2048;
        int lane = e3 >> 3, j = e3 & 7;
        int k = (lane >> 4) * 8 + j;
        int n = lane & 15;
        wfrag3[e3] = f2bf(w3[k * 16 + n]);
    } else if (e < 12288 + 2048 + 512 + 64) {
        int n = e - 12288 - 2048 - 512;
        float s = b1[n];
        for (int jj = 0; jj < 64; jj++) s += b_lin[jj] * w1[jj * 64 + n];
        b_eff[n] = s;
    }
}

// ---------------- main fused gather + MFMA MLP ----------------
__global__ __launch_bounds__(256) void fbseg_kernel(
    const float* __restrict__ p0, const float* __restrict__ p1,
    const float* __restrict__ fl,
    const int2* __restrict__ sorted,
    const u16* __restrict__ wfrag1, const u16* __restrict__ wfrag2,
    const u16* __restrict__ wfrag3, const float* __restrict__ b_eff,
    const float* __restrict__ b2, const float* __restrict__ b3,
    const float* __restrict__ w4, const float* __restrict__ b4,
    float* __restrict__ out)
{
    __shared__ __align__(16) u16 smem[21504];
    u16* feat = smem;                 // [64][FSTR]
    u16* H1   = smem + 64 * FSTR;     // [4][16][H1S]
    u16* H2   = H1 + 4 * 16 * H1S;    // [4][16][H2S]
    u16* H3   = H2 + 4 * 16 * H2S;    // [4][16][H3S]

    const int tid = threadIdx.x;
    const int p_base = blockIdx.x * 64;

    // ---- gather phase: 64 points x 192 channels -> LDS bf16 ----
    {
        const int pt = tid & 63;
        const int cs = tid >> 6;  // 0..3
        const int2 e = sorted[p_base + pt];
        const int b = e.x / NPTS;
        const int r = (e.y >> 9) & 511;
        const int c = e.y & 511;
        const size_t base = (size_t)b * ((size_t)64 * MAPHW) + (size_t)r * MAPW + (size_t)c;
        const float* maps[3] = {p0 + base, p1 + base, fl + base};
        #pragma unroll
        for (int m = 0; m < 3; m++) {
            const float* mp = maps[m];
            float v[16];
            #pragma unroll
            for (int u = 0; u < 16; u++) v[u] = mp[(size_t)(cs + u * 4) * MAPHW];
            #pragma unroll
            for (int u = 0; u < 16; u++) feat[pt * FSTR + m * 64 + cs + u * 4] = f2bf(v[u]);
        }
    }
    __syncthreads();

    // ---- MFMA phase: wave wv owns points m0..m0+15 ----
    const int wv = tid >> 6;
    const int lane = tid & 63;
    const int m0 = wv * 16;
    const int lr = lane & 15;   // D col / A row
    const int lq = lane >> 4;   // quad

    // layer 1: K=192 -> N=64
    f32x4 acc1[4] = {};
    #pragma unroll
    for (int kk = 0; kk < 6; kk++) {
        sh8 a = *(const sh8*)&feat[(m0 + lr) * FSTR + kk * 32 + lq * 8];
        #pragma unroll
        for (int nt = 0; nt < 4; nt++) {
            sh8 bfr = *(const sh8*)(wfrag1 + ((kk * 4 + nt) * 64 + lane) * 8);
            acc1[nt] = __builtin_amdgcn_mfma_f32_16x16x32_bf16(a, bfr, acc1[nt], 0, 0, 0);
        }
    }
    u16* H1w = H1 + wv * 16 * H1S;
    #pragma unroll
    for (int nt = 0; nt < 4; nt++) {
        const int n = nt * 16 + lr;
        const float bias = b_eff[n];
        #pragma unroll
        for (int rg = 0; rg < 4; rg++) {
            const int row = lq * 4 + rg;
            H1w[row * H1S + n] = f2bf(gelu_f(acc1[nt][rg] + bias));
        }
    }

    // layer 2: K=64 -> N=32
    f32x4 acc2[2] = {};
    #pragma unroll
    for (int kk = 0; kk < 2; kk++) {
        sh8 a = *(const sh8*)&H1w[lr * H1S + kk * 32 + lq * 8];
        #pragma unroll
        for (int nt = 0; nt < 2; nt++) {
            sh8 bfr = *(const sh8*)(wfrag2 + ((kk * 2 + nt) * 64 + lane) * 8);
            acc2[nt] = __builtin_amdgcn_mfma_f32_16x16x32_bf16(a, bfr, acc2[nt], 0, 0, 0);
        }
    }
    u16* H2w = H2 + wv * 16 * H2S;
    #pragma unroll
    for (int nt = 0; nt < 2; nt++) {
        const int n = nt * 16 + lr;
        const float bias = b2[n];
        #pragma unroll
        for (int rg = 0; rg < 4; rg++) {
            const int row = lq * 4 + rg;
            H2w[row * H2S + n] = f2bf(gelu_f(acc2[nt][rg] + bias));
        }
    }

    // layer 3: K=32 -> N=16
    f32x4 acc3 = {};
    {
        sh8 a = *(const sh8*)&H2w[lr * H2S + lq * 8];
        sh8 bfr = *(const sh8*)(wfrag3 + lane * 8);
        acc3 = __builtin_amdgcn_mfma_f32_16x16x32_bf16(a, bfr, acc3, 0, 0, 0);
    }
    u16* H3w = H3 + wv * 16 * H3S;
    {
        const float bias = b3[lr];
        #pragma unroll
        for (int rg = 0; rg < 4; rg++) {
            const int row = lq * 4 + rg;
            H3w[row * H3S + lr] = f2bf(gelu_f(acc3[rg] + bias));
        }
    }

    // layer 4 + sigmoid: lanes 0..15 each finish one point
    if (lane < 16) {
        float s = b4[0];
        #pragma unroll
        for (int k = 0; k < 16; k++) s = fmaf(bf2f(H3w[lane * H3S + k]), w4[k], s);
        const int orig = sorted[p_base + m0 + lane].x;
        out[orig] = 1.0f / (1.0f + expf(-s));
    }
}

extern "C" void kernel_launch(void* const* d_in, const int* in_sizes, int n_in,
                              void* d_out, int out_size, void* d_ws, size_t ws_size,
                              hipStream_t stream) {
    const float* p0    = (const float*)d_in[0];
    const float* p1    = (const float*)d_in[1];
    const float* fl    = (const float*)d_in[2];
    const int*   lidar = (const int*)d_in[3];
    const int*   radar = (const int*)d_in[4];
    const float* w_lin = (const float*)d_in[5];
    const float* b_lin = (const float*)d_in[6];
    const float* w1    = (const float*)d_in[7];
    const float* b1    = (const float*)d_in[8];
    const float* w2    = (const float*)d_in[9];
    const float* b2    = (const float*)d_in[10];
    const float* w3    = (const float*)d_in[11];
    const float* b3    = (const float*)d_in[12];
    const float* w4    = (const float*)d_in[13];
    const float* b4    = (const float*)d_in[14];
    float* out = (float*)d_out;

    // ws layout: hist | offs | sorted | wfrag1 | wfrag2 | wfrag3 | b_eff
    char* ws = (char*)d_ws;
    int*  hist   = (int*)ws;
    int*  offs   = (int*)(ws + NBINS * sizeof(int));
    int2* sorted = (int2*)(ws + 2 * NBINS * sizeof(int));
    char* wbase  = ws + 2 * NBINS * sizeof(int) + (size_t)NTOT * sizeof(int2);
    u16*  wfrag1 = (u16*)wbase;
    u16*  wfrag2 = (u16*)(wbase + 12288 * 2);
    u16*  wfrag3 = (u16*)(wbase + (12288 + 2048) * 2);
    float* b_eff = (float*)(wbase + (12288 + 2048 + 512) * 2);

    hipMemsetAsync(hist, 0, NBINS * sizeof(int), stream);
    hipLaunchKernelGGL(hist_kernel, dim3((NTOT + 255) / 256), dim3(256), 0, stream,
                       lidar, radar, hist);
    hipLaunchKernelGGL(scan_kernel, dim3(1), dim3(1024), 0, stream, hist, offs);
    hipLaunchKernelGGL(scatter_kernel, dim3((NTOT + 255) / 256), dim3(256), 0, stream,
                       lidar, radar, offs, sorted);
    hipLaunchKernelGGL(wprep_kernel, dim3((14912 + 255) / 256), dim3(256), 0, stream,
                       w_lin, b_lin, w1, b1, w2, w3, wfrag1, wfrag2, wfrag3, b_eff);
    hipLaunchKernelGGL(fbseg_kernel, dim3(NTOT / 64), dim3(256), 0, stream,
                       p0, p1, fl, sorted, wfrag1, wfrag2, wfrag3, b_eff,
                       b2, b3, w4, b4, out);
}

// Round 4
// 422.886 us; speedup vs baseline: 2.3163x; 1.0016x over previous
//
#include <hip/hip_runtime.h>
#include <math.h>

#define NPTS 120000
#define NLID 100000
#define NRAD 20000
#define NTOT (2 * NPTS)
#define MAPW 512
#define MAPHW (512 * 512)
#define NBINS 16384  // (b:1)(r:9)(c>>5:4)

typedef short sh8 __attribute__((ext_vector_type(8)));
typedef float f32x4 __attribute__((ext_vector_type(4)));
typedef unsigned short u16;
typedef unsigned int u32;

#define FROW 65   // feat_t row stride in floats; odd dword stride -> conflict-free
#define H1S 72    // 8*9  (odd m) -> aligned b128 reads, conflict-free
#define H2S 40    // 8*5
#define H3S 24    // 8*3
#define HWAVE (16 * (H1S + H2S + H3S))  // 2176 shorts per wave

__device__ __forceinline__ float gelu_f(float x) {
    return 0.5f * x * (1.0f + erff(x * 0.7071067811865476f));
}
__device__ __forceinline__ u16 f2bf(float f) {  // RNE
    unsigned int u = __float_as_uint(f);
    return (u16)((u + 0x7FFFu + ((u >> 16) & 1u)) >> 16);
}
__device__ __forceinline__ float bf2f(u16 h) {
    return __uint_as_float((unsigned int)h << 16);
}

// ---------------- sort chain (unchanged) ----------------
__device__ __forceinline__ void point_rc(int p, const int* __restrict__ lidar,
                                         const int* __restrict__ radar,
                                         int& b, int& r, int& c) {
    b = p / NPTS;
    int i = p - b * NPTS;
    if (i < NLID) {
        const int* cd = lidar + (size_t)(b * NLID + i) * 3;
        r = cd[1]; c = cd[2];
    } else {
        const int* cd = radar + (size_t)(b * NRAD + (i - NLID)) * 3;
        r = cd[1]; c = cd[2];
    }
}
__device__ __forceinline__ int bin_key(int b, int r, int c) {
    return (b << 13) | (r << 4) | (c >> 5);
}
__global__ void hist_kernel(const int* __restrict__ lidar, const int* __restrict__ radar,
                            int* __restrict__ hist) {
    int p = blockIdx.x * blockDim.x + threadIdx.x;
    if (p >= NTOT) return;
    int b, r, c; point_rc(p, lidar, radar, b, r, c);
    atomicAdd(&hist[bin_key(b, r, c)], 1);
}
__global__ __launch_bounds__(1024) void scan_kernel(const int* __restrict__ hist,
                                                    int* __restrict__ offs) {
    __shared__ int sums[1024];
    const int t = threadIdx.x;
    int local[16]; int s = 0;
    #pragma unroll
    for (int i = 0; i < 16; i++) { local[i] = hist[t * 16 + i]; s += local[i]; }
    sums[t] = s;
    __syncthreads();
    for (int off = 1; off < 1024; off <<= 1) {
        int add = (t >= off) ? sums[t - off] : 0;
        __syncthreads();
        sums[t] += add;
        __syncthreads();
    }
    int excl = (t == 0) ? 0 : sums[t - 1];
    #pragma unroll
    for (int i = 0; i < 16; i++) { offs[t * 16 + i] = excl; excl += local[i]; }
}
__global__ void scatter_kernel(const int* __restrict__ lidar, const int* __restrict__ radar,
                               int* __restrict__ offs, int2* __restrict__ sorted) {
    int p = blockIdx.x * blockDim.x + threadIdx.x;
    if (p >= NTOT) return;
    int b, r, c; point_rc(p, lidar, radar, b, r, c);
    int pos = atomicAdd(&offs[bin_key(b, r, c)], 1);
    sorted[pos] = make_int2(p, (r << 9) | c);
}

// ---------------- weight prep (unchanged): fuse lin+l1, B-frag swizzle ----------------
__global__ void wprep_kernel(const float* __restrict__ w_lin, const float* __restrict__ b_lin,
                             const float* __restrict__ w1, const float* __restrict__ b1,
                             const float* __restrict__ w2, const float* __restrict__ w3,
                             u16* __restrict__ wfrag1, u16* __restrict__ wfrag2,
                             u16* __restrict__ wfrag3, float* __restrict__ b_eff) {
    int e = blockIdx.x * blockDim.x + threadIdx.x;
    if (e < 12288) {
        int fi = e >> 9, r = e & 511, lane = r >> 3, j = r & 7;
        int kk = fi >> 2, nt = fi & 3;
        int k = kk * 32 + (lane >> 4) * 8 + j;
        int n = nt * 16 + (lane & 15);
        float val;
        if (k < 128) {
            float s = 0.f;
            for (int jj = 0; jj < 64; jj++) s += w_lin[k * 64 + jj] * w1[jj * 64 + n];
            val = s;
        } else {
            val = w1[(k - 64) * 64 + n];
        }
        wfrag1[e] = f2bf(val);
    } else if (e < 12288 + 2048) {
        int e2 = e - 12288;
        int fi = e2 >> 9, lane = (e2 >> 3) & 63, j = e2 & 7;
        int kk = fi >> 1, nt = fi & 1;
        int k = kk * 32 + (lane >> 4) * 8 + j;
        int n = nt * 16 + (lane & 15);
        wfrag2[e2] = f2bf(w2[k * 32 + n]);
    } else if (e < 12288 + 2048 + 512) {
        int e3 = e - 12288 - 2048;
        int lane = e3 >> 3, j = e3 & 7;
        int k = (lane >> 4) * 8 + j;
        int n = lane & 15;
        wfrag3[e3] = f2bf(w3[k * 16 + n]);
    } else if (e < 12288 + 2048 + 512 + 64) {
        int n = e - 12288 - 2048 - 512;
        float s = b1[n];
        for (int jj = 0; jj < 64; jj++) s += b_lin[jj] * w1[jj * 64 + n];
        b_eff[n] = s;
    }
}

// ---------------- main: async DMA gather (channel-major) + MFMA MLP ----------------
__global__ __launch_bounds__(256) void fbseg_kernel(
    const float* __restrict__ p0, const float* __restrict__ p1,
    const float* __restrict__ fl,
    const int2* __restrict__ sorted,
    const u16* __restrict__ wfrag1, const u16* __restrict__ wfrag2,
    const u16* __restrict__ wfrag3, const float* __restrict__ b_eff,
    const float* __restrict__ b2, const float* __restrict__ b3,
    const float* __restrict__ w4, const float* __restrict__ b4,
    float* __restrict__ out)
{
    // feat_t[ch][pt]: 192 rows x 64 f32, row stride FROW (odd dwords).
    // After layer 1 this region is dead; H1/H2/H3 alias into it (2nd barrier).
    __shared__ __align__(16) float smem[192 * FROW];  // 49920 B -> 3 blocks/CU

    const int tid = threadIdx.x;
    const int wv = tid >> 6;
    const int lane = tid & 63;
    const int p_base = blockIdx.x * 64;

    // ---- gather: each wave DMAs 48 channel-rows, lanes = 64 sorted points ----
    {
        const int2 e = sorted[p_base + lane];
        const int b = e.x / NPTS;
        const int r = (e.y >> 9) & 511;
        const int c = e.y & 511;
        const size_t off = (size_t)b * ((size_t)64 * MAPHW) + (size_t)r * MAPW + (size_t)c;
        const float* bases[3] = {p0 + off, p1 + off, fl + off};
        #pragma unroll
        for (int m = 0; m < 3; m++) {
            const float* gp = bases[m] + (size_t)wv * MAPHW;
            #pragma unroll
            for (int u = 0; u < 16; u++) {
                // wave-uniform channel row; readfirstlane pins it scalar
                const int chu = __builtin_amdgcn_readfirstlane(m * 64 + u * 4 + wv);
                __builtin_amdgcn_global_load_lds(
                    (const __attribute__((address_space(1))) u32*)gp,
                    (__attribute__((address_space(3))) u32*)(&smem[chu * FROW]),
                    4, 0, 0);
                gp += (size_t)4 * MAPHW;
            }
        }
    }
    __syncthreads();  // drains vmcnt (DMA complete) + barrier

    // ---- MFMA phase: wave wv owns points m0..m0+15 ----
    const int m0 = wv * 16;
    const int lr = lane & 15;
    const int lq = lane >> 4;
    const int col = m0 + lr;

    // layer 1: K=192 -> N=64 ; A built from feat_t columns (2-way max, free)
    f32x4 acc1[4] = {};
    #pragma unroll
    for (int kk = 0; kk < 6; kk++) {
        sh8 a;
        u16* ap = (u16*)&a;
        #pragma unroll
        for (int j = 0; j < 8; j++)
            ap[j] = f2bf(smem[(kk * 32 + lq * 8 + j) * FROW + col]);
        #pragma unroll
        for (int nt = 0; nt < 4; nt++) {
            sh8 bfr = *(const sh8*)(wfrag1 + ((kk * 4 + nt) * 64 + lane) * 8);
            acc1[nt] = __builtin_amdgcn_mfma_f32_16x16x32_bf16(a, bfr, acc1[nt], 0, 0, 0);
        }
    }
    __syncthreads();  // feat_t dead for ALL waves; reuse as per-wave H scratch

    u16* Hbase = (u16*)smem + wv * HWAVE;
    u16* H1w = Hbase;
    u16* H2w = Hbase + 16 * H1S;
    u16* H3w = Hbase + 16 * H1S + 16 * H2S;

    #pragma unroll
    for (int nt = 0; nt < 4; nt++) {
        const int n = nt * 16 + lr;
        const float bias = b_eff[n];
        #pragma unroll
        for (int rg = 0; rg < 4; rg++) {
            const int row = lq * 4 + rg;
            H1w[row * H1S + n] = f2bf(gelu_f(acc1[nt][rg] + bias));
        }
    }

    // layer 2: K=64 -> N=32
    f32x4 acc2[2] = {};
    #pragma unroll
    for (int kk = 0; kk < 2; kk++) {
        sh8 a = *(const sh8*)&H1w[lr * H1S + kk * 32 + lq * 8];
        #pragma unroll
        for (int nt = 0; nt < 2; nt++) {
            sh8 bfr = *(const sh8*)(wfrag2 + ((kk * 2 + nt) * 64 + lane) * 8);
            acc2[nt] = __builtin_amdgcn_mfma_f32_16x16x32_bf16(a, bfr, acc2[nt], 0, 0, 0);
        }
    }
    #pragma unroll
    for (int nt = 0; nt < 2; nt++) {
        const int n = nt * 16 + lr;
        const float bias = b2[n];
        #pragma unroll
        for (int rg = 0; rg < 4; rg++) {
            const int row = lq * 4 + rg;
            H2w[row * H2S + n] = f2bf(gelu_f(acc2[nt][rg] + bias));
        }
    }

    // layer 3: K=32 -> N=16
    f32x4 acc3 = {};
    {
        sh8 a = *(const sh8*)&H2w[lr * H2S + lq * 8];
        sh8 bfr = *(const sh8*)(wfrag3 + lane * 8);
        acc3 = __builtin_amdgcn_mfma_f32_16x16x32_bf16(a, bfr, acc3, 0, 0, 0);
    }
    {
        const float bias = b3[lr];
        #pragma unroll
        for (int rg = 0; rg < 4; rg++) {
            const int row = lq * 4 + rg;
            H3w[row * H3S + lr] = f2bf(gelu_f(acc3[rg] + bias));
        }
    }

    // layer 4 + sigmoid: lanes 0..15 finish one point each
    if (lane < 16) {
        float s = b4[0];
        #pragma unroll
        for (int k = 0; k < 16; k++) s = fmaf(bf2f(H3w[lane * H3S + k]), w4[k], s);
        const int orig = sorted[p_base + m0 + lane].x;
        out[orig] = 1.0f / (1.0f + expf(-s));
    }
}

extern "C" void kernel_launch(void* const* d_in, const int* in_sizes, int n_in,
                              void* d_out, int out_size, void* d_ws, size_t ws_size,
                              hipStream_t stream) {
    const float* p0    = (const float*)d_in[0];
    const float* p1    = (const float*)d_in[1];
    const float* fl    = (const float*)d_in[2];
    const int*   lidar = (const int*)d_in[3];
    const int*   radar = (const int*)d_in[4];
    const float* w_lin = (const float*)d_in[5];
    const float* b_lin = (const float*)d_in[6];
    const float* w1    = (const float*)d_in[7];
    const float* b1    = (const float*)d_in[8];
    const float* w2    = (const float*)d_in[9];
    const float* b2    = (const float*)d_in[10];
    const float* w3    = (const float*)d_in[11];
    const float* b3    = (const float*)d_in[12];
    const float* w4    = (const float*)d_in[13];
    const float* b4    = (const float*)d_in[14];
    float* out = (float*)d_out;

    // ws layout: hist | offs | sorted | wfrag1 | wfrag2 | wfrag3 | b_eff
    char* ws = (char*)d_ws;
    int*  hist   = (int*)ws;
    int*  offs   = (int*)(ws + NBINS * sizeof(int));
    int2* sorted = (int2*)(ws + 2 * NBINS * sizeof(int));
    char* wbase  = ws + 2 * NBINS * sizeof(int) + (size_t)NTOT * sizeof(int2);
    u16*  wfrag1 = (u16*)wbase;
    u16*  wfrag2 = (u16*)(wbase + 12288 * 2);
    u16*  wfrag3 = (u16*)(wbase + (12288 + 2048) * 2);
    float* b_eff = (float*)(wbase + (12288 + 2048 + 512) * 2);

    hipMemsetAsync(hist, 0, NBINS * sizeof(int), stream);
    hipLaunchKernelGGL(hist_kernel, dim3((NTOT + 255) / 256), dim3(256), 0, stream,
                       lidar, radar, hist);
    hipLaunchKernelGGL(scan_kernel, dim3(1), dim3(1024), 0, stream, hist, offs);
    hipLaunchKernelGGL(scatter_kernel, dim3((NTOT + 255) / 256), dim3(256), 0, stream,
                       lidar, radar, offs, sorted);
    hipLaunchKernelGGL(wprep_kernel, dim3((14912 + 255) / 256), dim3(256), 0, stream,
                       w_lin, b_lin, w1, b1, w2, w3, wfrag1, wfrag2, wfrag3, b_eff);
    hipLaunchKernelGGL(fbseg_kernel, dim3(NTOT / 64), dim3(256), 0, stream,
                       p0, p1, fl, sorted, wfrag1, wfrag2, wfrag3, b_eff,
                       b2, b3, w4, b4, out);
}